// Round 10
// baseline (225.569 us; speedup 1.0000x reference)
//
#include <hip/hip_runtime.h>

// PaDiM training-branch accumulation + finalize.
// embeddings: [B=32, C=192, P=3136] f32; means: [P,C] f32; covariances: [P,C,C] f32; n: int
// out: learned_means [P,C] ++ learned_covs [P,C,C]
//
// R10: barrier-free K2 with 3-tile rolling cov prefetch.
//  - K1 (transpose emb->Et bf16 [p][c][b]) now ALSO computes learned_means
//    (it has all B for each (c,p) in LDS): K2 loses the Et re-read, the
//    serial means phase, and its only __syncthreads.
//  - K2: 9 cov loads issued BEFORE the MFMAs (hidden under frag-wait+MFMA);
//    each epilogue tile prefetches tile ct+3 -> ~9 outstanding 16B loads per
//    thread (R8/R9 had 3, VGPR=44 proved no hoisting). ~110KB in flight/CU
//    at 12 waves -> HBM-saturating read pipeline.
//  - nt loads on cov (read-once; R6-proven safe), PLAIN stores (R9-proven:
//    R8's nt stores at 192B granularity doubled WRITE_SIZE).

#define BB 32
#define CC 192
#define PP 3136
#define II (BB * CC)   // 6144
#define EPSV 0.01f
#define WROW 52        // padded row stride (floats) of wave buffer (48+4)

typedef float f32x4 __attribute__((ext_vector_type(4)));
typedef short bf16x8 __attribute__((ext_vector_type(8)));

__device__ __forceinline__ unsigned short f2bf(float f) {
    unsigned int u = __float_as_uint(f);
    u += 0x7fffu + ((u >> 16) & 1u);        // round-to-nearest-even
    return (unsigned short)(u >> 16);
}
__device__ __forceinline__ float bf16val(unsigned short u) {
    return __uint_as_float(((unsigned int)u) << 16);
}

// ---- Kernel 1: emb [B,C,P] f32 -> Et [P][C][B] bf16, + learned_means ----
__global__ __launch_bounds__(256) void transpose_bf16(
    const float* __restrict__ emb, const float* __restrict__ means,
    const int* __restrict__ n_ptr,
    unsigned short* __restrict__ Et, float* __restrict__ out_means)
{
    __shared__ unsigned short tile[512 * 34];   // 34816 B
    const int c0 = blockIdx.x * 16;             // 12 blocks over C
    const int p0 = blockIdx.y * 32;             // 98 blocks over P
    const int t = threadIdx.x;
    const int tc = t & 31;                      // p lane
    const int rg = t >> 5;                      // 0..7

    #pragma unroll 8
    for (int k = 0; k < 64; ++k) {
        const int r = k * 8 + rg;               // r = cl*32 + b
        const int b = r & 31;
        const int cl = r >> 5;
        const float v = __builtin_nontemporal_load(
            &emb[(size_t)(b * CC + c0 + cl) * PP + (p0 + tc)]);
        tile[r * 34 + tc] = f2bf(v);
    }
    __syncthreads();

    // Et write: 8 x 128B contiguous segments per wave
    {
        const int pl = t >> 3;                  // 0..31
        unsigned short* dst = Et + (size_t)(p0 + pl) * II + c0 * 32;
        #pragma unroll
        for (int w = 0; w < 8; ++w) {
            const int q = w * 8 + (t & 7);      // 16B chunk index
            const int rbase = (q >> 2) * 32 + (q & 3) * 8;
            unsigned int dw[4];
            #pragma unroll
            for (int j = 0; j < 4; ++j) {
                const unsigned int lo = tile[(rbase + 2 * j) * 34 + pl];
                const unsigned int hi = tile[(rbase + 2 * j + 1) * 34 + pl];
                dw[j] = lo | (hi << 16);
            }
            uint4 val; val.x = dw[0]; val.y = dw[1]; val.z = dw[2]; val.w = dw[3];
            *reinterpret_cast<uint4*>(dst + q * 8) = val;
        }
    }

    // learned_means: thread (cl = t>>4, ph = t&15) sums over all 32 b for
    // two p's. 4-way LDS bank aliasing, 2.4MB RMW total -- cheap.
    {
        const float n_new = (float)(n_ptr[0] + BB);     // 128
        const float inv_nnew = 1.0f / n_new;
        const int cl = t >> 4;
        const int ph = t & 15;
        #pragma unroll
        for (int h = 0; h < 2; ++h) {
            const int pp = ph + 16 * h;
            float s = 0.f;
            #pragma unroll
            for (int b = 0; b < 32; ++b)
                s += bf16val(tile[(cl * 32 + b) * 34 + pp]);
            const size_t idx = (size_t)(p0 + pp) * CC + (c0 + cl);
            out_means[idx] = (means[idx] + s) * inv_nnew;
        }
    }
}

// ---- Kernel 2: MFMA SYRK + wave-private epilogue, barrier-free,
//      3-tile-deep rolling cov prefetch ----
__global__ __launch_bounds__(256, 3) void padim_mfma(
    const unsigned short* __restrict__ Et,  // [P][C][B] bf16
    const float* __restrict__ lmeans,       // [P,C] learned means (from K1)
    const float* __restrict__ covs,         // [P,C,C]
    const int*   __restrict__ n_ptr,
    float* __restrict__ out_covs)           // [P,C,C]
{
    __shared__ __align__(16) float wbuf[4][2][16 * WROW];   // 26624 B

    // XCD-bijective swizzle; the two slabs of one patch stay adjacent.
    const int bid = blockIdx.x;
    const int u = (bid & 7) * (PP * 2 / 8) + (bid >> 3);
    const int slab = u & 1;                 // c-slab: rows slab*96..+95
    const int p = u >> 1;

    const int t = threadIdx.x;
    const int lane = t & 63;
    const int w = t >> 6;                   // wave 0..3: owns cov cols [48w,48w+48)
    const int l15 = lane & 15;
    const int l4  = lane >> 4;

    const float n_new = (float)(n_ptr[0] + BB);       // 128
    const float inv_nm1 = 1.0f / (n_new - 1.0f);      // 1/127

    const unsigned short* __restrict__ Erow = Et + (size_t)p * II;

    // ---- Frag loads FIRST (L2/L3-resident): MFMA's vmcnt wait then leaves
    //      the later cov loads outstanding. Contiguous 1KB per wave instr.
    bf16x8 Af[3], Bf[6];
    #pragma unroll
    for (int dt = 0; dt < 3; ++dt) {
        const int rA = (3 * w + dt) * 16 + l15;
        Af[dt] = *reinterpret_cast<const bf16x8*>(Erow + rA * 32 + l4 * 8);
    }
    #pragma unroll
    for (int ct = 0; ct < 6; ++ct) {
        const int rB = (slab * 6 + ct) * 16 + l15;
        Bf[ct] = *reinterpret_cast<const bf16x8*>(Erow + rB * 32 + l4 * 8);
    }

    // ---- Per-lane epilogue geometry + mean reads (768B/patch, L2-hit) ----
    const float* __restrict__ mrow = lmeans + (size_t)p * CC;
    int rk[3], qk[3];
    f32x4 mdk[3];
    size_t offb[3];
    #pragma unroll
    for (int k = 0; k < 3; ++k) {
        const int chunk = k * 64 + lane;           // 0..191 over [16][12] chunks
        rk[k] = chunk / 12;
        qk[k] = chunk - rk[k] * 12;
        mdk[k] = *reinterpret_cast<const f32x4*>(&mrow[48 * w + 4 * qk[k]]);
        offb[k] = (size_t)rk[k] * CC + 48 * w + 4 * qk[k];
    }
    float mck[6][3];
    #pragma unroll
    for (int ct = 0; ct < 6; ++ct)
        #pragma unroll
        for (int k = 0; k < 3; ++k)
            mck[ct][k] = mrow[(slab * 6 + ct) * 16 + rk[k]];

    // ---- Rolling cov prefetch: tiles 0..2 before the MFMAs ----
    const float* __restrict__ cov_p = covs + (size_t)p * CC * CC;
    float* __restrict__ out_p = out_covs + (size_t)p * CC * CC;

    f32x4 cin[6][3];
    #pragma unroll
    for (int ct = 0; ct < 3; ++ct)
        #pragma unroll
        for (int k = 0; k < 3; ++k)
            cin[ct][k] = __builtin_nontemporal_load(reinterpret_cast<const f32x4*>(
                cov_p + (size_t)((slab * 6 + ct) * 16) * CC + offb[k]));

    // ---- 18 MFMAs (full K=32 per tile) ----
    f32x4 acc[3][6];
    #pragma unroll
    for (int dt = 0; dt < 3; ++dt)
        #pragma unroll
        for (int ct = 0; ct < 6; ++ct)
            acc[dt][ct] = (f32x4){0.f, 0.f, 0.f, 0.f};

    #pragma unroll
    for (int ct = 0; ct < 6; ++ct)
        #pragma unroll
        for (int dt = 0; dt < 3; ++dt)
            acc[dt][ct] = __builtin_amdgcn_mfma_f32_16x16x32_bf16(
                Af[dt], Bf[ct], acc[dt][ct], 0, 0, 0);

    // ---- Wave-private epilogue: per tile, prefetch ct+3, LDS transpose,
    //      fused finalize, plain coalesced store (192B segments). ----
    #pragma unroll
    for (int ct = 0; ct < 6; ++ct) {
        if (ct + 3 < 6) {
            #pragma unroll
            for (int k = 0; k < 3; ++k)
                cin[ct + 3][k] = __builtin_nontemporal_load(reinterpret_cast<const f32x4*>(
                    cov_p + (size_t)((slab * 6 + ct + 3) * 16) * CC + offb[k]));
        }
        const int cbase = (slab * 6 + ct) * 16;
        float* buf = &wbuf[w][ct & 1][0];

        #pragma unroll
        for (int dt = 0; dt < 3; ++dt)
            *reinterpret_cast<f32x4*>(&buf[l15 * WROW + (dt * 4 + l4) * 4]) = acc[dt][ct];

        #pragma unroll
        for (int k = 0; k < 3; ++k) {
            const f32x4 a = *reinterpret_cast<const f32x4*>(&buf[rk[k] * WROW + 4 * qk[k]]);
            const int c = cbase + rk[k];
            const float nmc = n_new * mck[ct][k];
            f32x4 o = (cin[ct][k] + a - nmc * mdk[k]) * inv_nm1;
            const int dd = c - (48 * w + 4 * qk[k]);   // diagonal when 0<=dd<4
            o.x += (dd == 0) ? EPSV : 0.f;
            o.y += (dd == 1) ? EPSV : 0.f;
            o.z += (dd == 2) ? EPSV : 0.f;
            o.w += (dd == 3) ? EPSV : 0.f;
            *reinterpret_cast<f32x4*>(out_p + (size_t)cbase * CC + offb[k]) = o;
        }
    }
}

// ---------- Fallback (ws too small): single-kernel with direct gather ----
__global__ __launch_bounds__(256, 3) void padim_fallback(
    const float* __restrict__ emb, const float* __restrict__ means,
    const float* __restrict__ covs, const int* __restrict__ n_ptr,
    float* __restrict__ out_means, float* __restrict__ out_covs)
{
    __shared__ __align__(16) float E[II];
    __shared__ __align__(16) float m[CC];
    const int bid = blockIdx.x;
    const int p = (bid & 7) * (PP / 8) + (bid >> 3);
    const int t = threadIdx.x;
    const float n_new = (float)(n_ptr[0] + BB);
    const float inv_nnew = 1.0f / n_new;
    const float inv_nm1 = 1.0f / (n_new - 1.0f);
    #pragma unroll
    for (int k = 0; k < II / 256; ++k) {
        const int i = t + k * 256;
        E[i] = emb[(size_t)i * PP + p];
    }
    __syncthreads();
    if (t < CC) {
        float s = 0.0f;
        #pragma unroll
        for (int b = 0; b < BB; ++b) s += E[b * CC + t];
        const float mm = (means[(size_t)p * CC + t] + s) * inv_nnew;
        m[t] = mm;
        out_means[(size_t)p * CC + t] = mm;
    }
    __syncthreads();
    const int tx = t & 15, ty = t >> 4;
    const int dbase0 = tx * 4;
    const float* __restrict__ cov_p = covs + (size_t)p * CC * CC;
    float* __restrict__ out_p = out_covs + (size_t)p * CC * CC;
    float md[12];
    *reinterpret_cast<float4*>(&md[0]) = *reinterpret_cast<const float4*>(&m[dbase0]);
    *reinterpret_cast<float4*>(&md[4]) = *reinterpret_cast<const float4*>(&m[64 + dbase0]);
    *reinterpret_cast<float4*>(&md[8]) = *reinterpret_cast<const float4*>(&m[128 + dbase0]);
    #pragma unroll
    for (int pass = 0; pass < 2; ++pass) {
        const int c0 = pass * 96 + ty * 6;
        float acc[6][12];
        #pragma unroll
        for (int i = 0; i < 6; ++i)
            #pragma unroll
            for (int j = 0; j < 12; ++j) acc[i][j] = 0.f;
        #pragma unroll 4
        for (int b = 0; b < BB; ++b) {
            const float* __restrict__ Eb = E + b * CC;
            float cs[6], ds[12];
            *reinterpret_cast<float4*>(&ds[0]) = *reinterpret_cast<const float4*>(&Eb[dbase0]);
            *reinterpret_cast<float4*>(&ds[4]) = *reinterpret_cast<const float4*>(&Eb[64 + dbase0]);
            *reinterpret_cast<float4*>(&ds[8]) = *reinterpret_cast<const float4*>(&Eb[128 + dbase0]);
            *reinterpret_cast<float2*>(&cs[0]) = *reinterpret_cast<const float2*>(&Eb[c0]);
            *reinterpret_cast<float2*>(&cs[2]) = *reinterpret_cast<const float2*>(&Eb[c0 + 2]);
            *reinterpret_cast<float2*>(&cs[4]) = *reinterpret_cast<const float2*>(&Eb[c0 + 4]);
            #pragma unroll
            for (int i = 0; i < 6; ++i)
                #pragma unroll
                for (int j = 0; j < 12; ++j)
                    acc[i][j] = fmaf(cs[i], ds[j], acc[i][j]);
        }
        float mc[6];
        *reinterpret_cast<float2*>(&mc[0]) = *reinterpret_cast<const float2*>(&m[c0]);
        *reinterpret_cast<float2*>(&mc[2]) = *reinterpret_cast<const float2*>(&m[c0 + 2]);
        *reinterpret_cast<float2*>(&mc[4]) = *reinterpret_cast<const float2*>(&m[c0 + 4]);
        #pragma unroll
        for (int i = 0; i < 6; ++i) {
            const int c = c0 + i;
            const size_t row = (size_t)c * CC;
            const float nmc = n_new * mc[i];
            #pragma unroll
            for (int g = 0; g < 3; ++g) {
                const int db = g * 64 + dbase0;
                const float4 cin = *reinterpret_cast<const float4*>(&cov_p[row + db]);
                float4 o;
                o.x = (cin.x + acc[i][g*4+0] - nmc * md[g*4+0]) * inv_nm1;
                o.y = (cin.y + acc[i][g*4+1] - nmc * md[g*4+1]) * inv_nm1;
                o.z = (cin.z + acc[i][g*4+2] - nmc * md[g*4+2]) * inv_nm1;
                o.w = (cin.w + acc[i][g*4+3] - nmc * md[g*4+3]) * inv_nm1;
                const int dd = c - db;
                if (dd == 0) o.x += EPSV;
                if (dd == 1) o.y += EPSV;
                if (dd == 2) o.z += EPSV;
                if (dd == 3) o.w += EPSV;
                *reinterpret_cast<float4*>(&out_p[row + db]) = o;
            }
        }
    }
}

extern "C" void kernel_launch(void* const* d_in, const int* in_sizes, int n_in,
                              void* d_out, int out_size, void* d_ws, size_t ws_size,
                              hipStream_t stream) {
    const float* emb   = (const float*)d_in[0];
    const float* means = (const float*)d_in[1];
    const float* covs  = (const float*)d_in[2];
    const int*   n_ptr = (const int*)d_in[3];

    float* out_means = (float*)d_out;                      // [P,C]
    float* out_covs  = (float*)d_out + (size_t)PP * CC;    // [P,C,C]

    const size_t et_bytes = (size_t)PP * II * sizeof(unsigned short);   // 38.5 MB
    if (ws_size >= et_bytes) {
        unsigned short* Et = (unsigned short*)d_ws;
        hipLaunchKernelGGL(transpose_bf16, dim3(CC / 16, PP / 32), dim3(256),
                           0, stream, emb, means, n_ptr, Et, out_means);
        hipLaunchKernelGGL(padim_mfma, dim3(PP * 2), dim3(256), 0, stream,
                           Et, out_means, covs, n_ptr, out_covs);
    } else {
        hipLaunchKernelGGL(padim_fallback, dim3(PP), dim3(256), 0, stream,
                           emb, means, covs, n_ptr, out_means, out_covs);
    }
}